// Round 1
// baseline (9011.154 us; speedup 1.0000x reference)
//
#include <hip/hip_runtime.h>

// ---------------------------------------------------------------------------
// MultiLayerNormGRU on MI355X (gfx950)
//
// Structure: persistent blocks. Each block owns R_=16 batch rows and runs the
// full T=512 recurrence locally (batch rows are independent -> no grid sync).
// Per step, per layer: gates GEMM (MFMA bf16 16x16x32) -> LN (cross-wave LDS
// partials) -> r,z -> candidate GEMM -> LN -> tanh -> h update.
// h state: fp32 in registers of owner lanes. bf16 copies of [x|h] in LDS are
// the MFMA A-source. Weights: pre-swizzled bf16 fragments in d_ws, streamed
// from L2 every step (1.28 MB/block/step -> this round is stream-bound).
// ---------------------------------------------------------------------------

#define B_   512
#define T_   512
#define DIN  64
#define H_   256
#define OUT_ 64
#define R_   16            // batch rows per block (one MFMA M tile)
#define NBLK (B_ / R_)     // 32 blocks
#define KC0  10            // K-chunks of 32 for layer0 (K=320)
#define KC1  16            // layer1 (K=512)
#define EPS_ 1e-5f

typedef __attribute__((ext_vector_type(8))) short bf16x8;
typedef __attribute__((ext_vector_type(4))) float f32x4;

__device__ __forceinline__ unsigned short f2bf(float f) {
  unsigned int u = __float_as_uint(f);
  u += 0x7fffu + ((u >> 16) & 1u);          // RNE f32 -> bf16 (finite inputs)
  return (unsigned short)(u >> 16);
}
__device__ __forceinline__ float sigm(float xv) { return 1.f / (1.f + __expf(-xv)); }
__device__ __forceinline__ float tanh_fast(float xv) {
  xv = fminf(fmaxf(xv, -15.f), 15.f);
  float e = __expf(-2.f * xv);
  return (1.f - e) / (1.f + e);
}

struct CellParams {           // per-lane column constants, hoisted out of T-loop
  float bg_r0, bg_r1, bg_z0, bg_z1;     // gate bias (r cols, z cols)
  float gw_r0, gw_r1, gw_z0, gw_z1;     // gate LN gamma
  float gb_r0, gb_r1, gb_z0, gb_z1;     // gate LN beta
  float bc_0, bc_1, cw_0, cw_1, cb_0, cb_1; // cand bias / LN gamma / LN beta
};

// One LayerNormGRU cell for R_=16 rows. comb holds [x_or_h0 | h] as bf16,
// h-part at column HOFF. hm = fp32 h master (owner-lane registers).
// Wave w owns gate ntiles {2w,2w+1,16+2w,17+2w} and cand ntiles {2w,2w+1};
// z tiles and cand tiles share the same (lane,reg)->(row,col) map, so the
// update runs fully in-register.
template<int KC, int CW, int HOFF>
__device__ __forceinline__ void gru_cell(
    unsigned short (&comb)[R_][CW],
    const unsigned short* __restrict__ wgf,
    const unsigned short* __restrict__ wcf,
    const CellParams& p,
    float (&hm)[2][4],
    unsigned short* hcopy, int hcopy_stride,
    float (&sumP)[8][16], float (&sqP)[8][16])
{
  const int lane  = threadIdx.x & 63;
  const int wv    = threadIdx.x >> 6;
  const int arow  = lane & 15;          // A-frag row
  const int koff  = (lane >> 4) * 8;    // A-frag k offset
  const int crow0 = (lane >> 4) * 4;    // C-frag first row
  const int colr0 = 32 * wv + (lane & 15), colr1 = colr0 + 16;
  const int nt0 = 2 * wv, nt1 = 2 * wv + 1, nt2 = 16 + 2 * wv, nt3 = 17 + 2 * wv;

  // ---- gates GEMM: [16 x 32K] @ Wg^T -> [16 x 512] ----
  f32x4 a0 = {0,0,0,0}, a1 = {0,0,0,0}, a2 = {0,0,0,0}, a3 = {0,0,0,0};
#pragma unroll 2
  for (int kc = 0; kc < KC; ++kc) {
    bf16x8 av = *reinterpret_cast<const bf16x8*>(&comb[arow][kc * 32 + koff]);
    bf16x8 b0 = *reinterpret_cast<const bf16x8*>(wgf + ((nt0 * KC + kc) * 64 + lane) * 8);
    bf16x8 b1 = *reinterpret_cast<const bf16x8*>(wgf + ((nt1 * KC + kc) * 64 + lane) * 8);
    bf16x8 b2 = *reinterpret_cast<const bf16x8*>(wgf + ((nt2 * KC + kc) * 64 + lane) * 8);
    bf16x8 b3 = *reinterpret_cast<const bf16x8*>(wgf + ((nt3 * KC + kc) * 64 + lane) * 8);
    a0 = __builtin_amdgcn_mfma_f32_16x16x32_bf16(av, b0, a0, 0, 0, 0);
    a1 = __builtin_amdgcn_mfma_f32_16x16x32_bf16(av, b1, a1, 0, 0, 0);
    a2 = __builtin_amdgcn_mfma_f32_16x16x32_bf16(av, b2, a2, 0, 0, 0);
    a3 = __builtin_amdgcn_mfma_f32_16x16x32_bf16(av, b3, a3, 0, 0, 0);
  }
  {
    float s[4], q[4];
#pragma unroll
    for (int g = 0; g < 4; ++g) {
      a0[g] += p.bg_r0; a1[g] += p.bg_r1; a2[g] += p.bg_z0; a3[g] += p.bg_z1;
      s[g] = a0[g] + a1[g] + a2[g] + a3[g];
      q[g] = a0[g]*a0[g] + a1[g]*a1[g] + a2[g]*a2[g] + a3[g]*a3[g];
    }
#pragma unroll
    for (int m = 1; m < 16; m <<= 1) {
#pragma unroll
      for (int g = 0; g < 4; ++g) { s[g] += __shfl_xor(s[g], m, 64); q[g] += __shfl_xor(q[g], m, 64); }
    }
    if ((lane & 15) == 0) {
#pragma unroll
      for (int g = 0; g < 4; ++g) { sumP[wv][crow0 + g] = s[g]; sqP[wv][crow0 + g] = q[g]; }
    }
  }
  __syncthreads();

  // ---- gate LN stats (redundant per wave), r,z; write r*h into comb ----
  float zf[2][4];
  {
    const int rr = lane & 15;
    float S = 0.f, Q = 0.f;
#pragma unroll
    for (int w = 0; w < 8; ++w) { S += sumP[w][rr]; Q += sqP[w][rr]; }
    float mn = S * (1.f / 512.f);
    float rs = rsqrtf(Q * (1.f / 512.f) - mn * mn + EPS_);
#pragma unroll
    for (int g = 0; g < 4; ++g) {
      float m_ = __shfl(mn, crow0 + g, 64);
      float r_ = __shfl(rs, crow0 + g, 64);
      float r0 = sigm((a0[g] - m_) * r_ * p.gw_r0 + p.gb_r0);
      float r1 = sigm((a1[g] - m_) * r_ * p.gw_r1 + p.gb_r1);
      comb[crow0 + g][HOFF + colr0] = f2bf(r0 * hm[0][g]);
      comb[crow0 + g][HOFF + colr1] = f2bf(r1 * hm[1][g]);
      zf[0][g] = sigm((a2[g] - m_) * r_ * p.gw_z0 + p.gb_z0);
      zf[1][g] = sigm((a3[g] - m_) * r_ * p.gw_z1 + p.gb_z1);
    }
  }
  __syncthreads();

  // ---- candidate GEMM: [16 x 32K] @ Wc^T -> [16 x 256] ----
  f32x4 c0 = {0,0,0,0}, c1 = {0,0,0,0};
#pragma unroll 2
  for (int kc = 0; kc < KC; ++kc) {
    bf16x8 av = *reinterpret_cast<const bf16x8*>(&comb[arow][kc * 32 + koff]);
    bf16x8 b0 = *reinterpret_cast<const bf16x8*>(wcf + ((nt0 * KC + kc) * 64 + lane) * 8);
    bf16x8 b1 = *reinterpret_cast<const bf16x8*>(wcf + ((nt1 * KC + kc) * 64 + lane) * 8);
    c0 = __builtin_amdgcn_mfma_f32_16x16x32_bf16(av, b0, c0, 0, 0, 0);
    c1 = __builtin_amdgcn_mfma_f32_16x16x32_bf16(av, b1, c1, 0, 0, 0);
  }
  {
    float s[4], q[4];
#pragma unroll
    for (int g = 0; g < 4; ++g) {
      c0[g] += p.bc_0; c1[g] += p.bc_1;
      s[g] = c0[g] + c1[g];
      q[g] = c0[g]*c0[g] + c1[g]*c1[g];
    }
#pragma unroll
    for (int m = 1; m < 16; m <<= 1) {
#pragma unroll
      for (int g = 0; g < 4; ++g) { s[g] += __shfl_xor(s[g], m, 64); q[g] += __shfl_xor(q[g], m, 64); }
    }
    if ((lane & 15) == 0) {
#pragma unroll
      for (int g = 0; g < 4; ++g) { sumP[wv][crow0 + g] = s[g]; sqP[wv][crow0 + g] = q[g]; }
    }
  }
  __syncthreads();

  // ---- cand LN, tanh, h update (in-register), publish bf16 h ----
  {
    const int rr = lane & 15;
    float S = 0.f, Q = 0.f;
#pragma unroll
    for (int w = 0; w < 8; ++w) { S += sumP[w][rr]; Q += sqP[w][rr]; }
    float mn = S * (1.f / 256.f);
    float rs = rsqrtf(Q * (1.f / 256.f) - mn * mn + EPS_);
#pragma unroll
    for (int g = 0; g < 4; ++g) {
      float m_ = __shfl(mn, crow0 + g, 64);
      float r_ = __shfl(rs, crow0 + g, 64);
      float n0 = tanh_fast((c0[g] - m_) * r_ * p.cw_0 + p.cb_0);
      float n1 = tanh_fast((c1[g] - m_) * r_ * p.cw_1 + p.cb_1);
      float h0n = (1.f - zf[0][g]) * hm[0][g] + zf[0][g] * n0;
      float h1n = (1.f - zf[1][g]) * hm[1][g] + zf[1][g] * n1;
      hm[0][g] = h0n; hm[1][g] = h1n;
      unsigned short hb0 = f2bf(h0n), hb1 = f2bf(h1n);
      comb[crow0 + g][HOFF + colr0] = hb0;
      comb[crow0 + g][HOFF + colr1] = hb1;
      if (hcopy) {
        hcopy[(crow0 + g) * hcopy_stride + colr0] = hb0;
        hcopy[(crow0 + g) * hcopy_stride + colr1] = hb1;
      }
    }
  }
  __syncthreads();
}

// --------------------------- prep: weight fragments -------------------------
// W [N][K] fp32 -> bf16 MFMA B-fragments, linear per (ntile, kchunk):
// dst[((nt*KC + kc)*64 + lane)*8 + elem], lane = (n&15) + 16*((k>>3)&3),
// elem = k&7. Streaming loads in the main kernel are then 1KB/wave, coalesced.
__global__ void prep_w(const float* __restrict__ w, unsigned short* __restrict__ dst,
                       int N, int K) {
  int gid = blockIdx.x * 256 + threadIdx.x;
  if (gid >= N * K) return;
  int n = gid / K, k = gid - n * K;
  int KC = K >> 5;
  int idx = (((n >> 4) * KC + (k >> 5)) * 64 + ((n & 15) + 16 * ((k >> 3) & 3))) * 8 + (k & 7);
  dst[idx] = f2bf(w[gid]);
}

// --------------------------------- main -------------------------------------
__launch_bounds__(512, 2)
__global__ void gru_main(
    const float* __restrict__ x,
    const unsigned short* __restrict__ wg0f, const unsigned short* __restrict__ wc0f,
    const unsigned short* __restrict__ wg1f, const unsigned short* __restrict__ wc1f,
    const float* __restrict__ bg0, const float* __restrict__ gnw0, const float* __restrict__ gnb0,
    const float* __restrict__ bc0, const float* __restrict__ cnw0, const float* __restrict__ cnb0,
    const float* __restrict__ bg1, const float* __restrict__ gnw1, const float* __restrict__ gnb1,
    const float* __restrict__ bc1, const float* __restrict__ cnw1, const float* __restrict__ cnb1,
    const float* __restrict__ fcW, const float* __restrict__ fcb,
    float* __restrict__ out)
{
  __shared__ __align__(16) unsigned short comb0[R_][328];  // [x(64) | h0(256)] +pad8
  __shared__ __align__(16) unsigned short comb1[R_][520];  // [h0(256)|h1(256)] +pad8
  __shared__ float sumP[8][16];
  __shared__ float sqP[8][16];
  __shared__ float h1dump[R_][H_];

  const int tid  = threadIdx.x;
  const int lane = tid & 63;
  const int wv   = tid >> 6;
  const int b0   = blockIdx.x * R_;
  const int colr0 = 32 * wv + (lane & 15), colr1 = colr0 + 16;

  for (int i = tid; i < R_ * 328; i += 512) (&comb0[0][0])[i] = 0;
  for (int i = tid; i < R_ * 520; i += 512) (&comb1[0][0])[i] = 0;

  float h0m[2][4] = {{0,0,0,0},{0,0,0,0}};
  float h1m[2][4] = {{0,0,0,0},{0,0,0,0}};

  CellParams p0, p1;
  p0.bg_r0 = bg0[colr0];  p0.bg_r1 = bg0[colr1];  p0.bg_z0 = bg0[256+colr0];  p0.bg_z1 = bg0[256+colr1];
  p0.gw_r0 = gnw0[colr0]; p0.gw_r1 = gnw0[colr1]; p0.gw_z0 = gnw0[256+colr0]; p0.gw_z1 = gnw0[256+colr1];
  p0.gb_r0 = gnb0[colr0]; p0.gb_r1 = gnb0[colr1]; p0.gb_z0 = gnb0[256+colr0]; p0.gb_z1 = gnb0[256+colr1];
  p0.bc_0 = bc0[colr0];   p0.bc_1 = bc0[colr1];
  p0.cw_0 = cnw0[colr0];  p0.cw_1 = cnw0[colr1];
  p0.cb_0 = cnb0[colr0];  p0.cb_1 = cnb0[colr1];
  p1.bg_r0 = bg1[colr0];  p1.bg_r1 = bg1[colr1];  p1.bg_z0 = bg1[256+colr0];  p1.bg_z1 = bg1[256+colr1];
  p1.gw_r0 = gnw1[colr0]; p1.gw_r1 = gnw1[colr1]; p1.gw_z0 = gnw1[256+colr0]; p1.gw_z1 = gnw1[256+colr1];
  p1.gb_r0 = gnb1[colr0]; p1.gb_r1 = gnb1[colr1]; p1.gb_z0 = gnb1[256+colr0]; p1.gb_z1 = gnb1[256+colr1];
  p1.bc_0 = bc1[colr0];   p1.bc_1 = bc1[colr1];
  p1.cw_0 = cnw1[colr0];  p1.cw_1 = cnw1[colr1];
  p1.cb_0 = cnb1[colr0];  p1.cb_1 = cnb1[colr1];

  __syncthreads();

  for (int t = 0; t < T_; ++t) {
    // stage x_t (bf16) into comb0[:,0:64]
    if (tid < 256) {
      int r = tid >> 4, c4 = (tid & 15) * 4;
      const float4 v = *reinterpret_cast<const float4*>(
          x + (((size_t)(b0 + r)) * T_ + t) * DIN + c4);
      ushort4 o4;
      o4.x = f2bf(v.x); o4.y = f2bf(v.y); o4.z = f2bf(v.z); o4.w = f2bf(v.w);
      *reinterpret_cast<ushort4*>(&comb0[r][c4]) = o4;
    }
    __syncthreads();
    gru_cell<KC0, 328, 64>(comb0, wg0f, wc0f, p0, h0m, &comb1[0][0], 520, sumP, sqP);
    gru_cell<KC1, 520, 256>(comb1, wg1f, wc1f, p1, h1m, (unsigned short*)nullptr, 0, sumP, sqP);
  }

  // dump final h1 (fp32 masters) and apply the FC head
  {
    const int crow0 = (lane >> 4) * 4;
#pragma unroll
    for (int g = 0; g < 4; ++g) {
      h1dump[crow0 + g][colr0] = h1m[0][g];
      h1dump[crow0 + g][colr1] = h1m[1][g];
    }
  }
  __syncthreads();
  {
    int r = tid >> 5;              // 0..15
    int o = (tid & 31) * 2;        // 0..62
    float acc0 = fcb[o], acc1 = fcb[o + 1];
    for (int k = 0; k < H_; ++k) {
      float h = h1dump[r][k];
      acc0 = fmaf(h, fcW[o * H_ + k], acc0);
      acc1 = fmaf(h, fcW[(o + 1) * H_ + k], acc1);
    }
    out[((size_t)(b0 + r)) * OUT_ + o]     = acc0;
    out[((size_t)(b0 + r)) * OUT_ + o + 1] = acc1;
  }
}

extern "C" void kernel_launch(void* const* d_in, const int* in_sizes, int n_in,
                              void* d_out, int out_size, void* d_ws, size_t ws_size,
                              hipStream_t stream) {
  (void)in_sizes; (void)n_in; (void)out_size; (void)ws_size;
  const float* x    = (const float*)d_in[0];
  const float* Wg0  = (const float*)d_in[1];
  const float* bg0  = (const float*)d_in[2];
  const float* gnw0 = (const float*)d_in[3];
  const float* gnb0 = (const float*)d_in[4];
  const float* Wc0  = (const float*)d_in[5];
  const float* bc0  = (const float*)d_in[6];
  const float* cnw0 = (const float*)d_in[7];
  const float* cnb0 = (const float*)d_in[8];
  const float* Wg1  = (const float*)d_in[9];
  const float* bg1  = (const float*)d_in[10];
  const float* gnw1 = (const float*)d_in[11];
  const float* gnb1 = (const float*)d_in[12];
  const float* Wc1  = (const float*)d_in[13];
  const float* bc1  = (const float*)d_in[14];
  const float* cnw1 = (const float*)d_in[15];
  const float* cnb1 = (const float*)d_in[16];
  const float* fcW  = (const float*)d_in[17];
  const float* fcb  = (const float*)d_in[18];

  // workspace: bf16 weight fragments (total 1,277,952 ushorts = 2.56 MB)
  unsigned short* wg0f = (unsigned short*)d_ws;
  unsigned short* wc0f = wg0f + 512 * 320;
  unsigned short* wg1f = wc0f + 256 * 320;
  unsigned short* wc1f = wg1f + 512 * 512;

  prep_w<<<640,  256, 0, stream>>>(Wg0, wg0f, 512, 320);
  prep_w<<<320,  256, 0, stream>>>(Wc0, wc0f, 256, 320);
  prep_w<<<1024, 256, 0, stream>>>(Wg1, wg1f, 512, 512);
  prep_w<<<512,  256, 0, stream>>>(Wc1, wc1f, 256, 512);

  gru_main<<<NBLK, 512, 0, stream>>>(x, wg0f, wc0f, wg1f, wc1f,
      bg0, gnw0, gnb0, bc0, cnw0, cnb0,
      bg1, gnw1, gnb1, bc1, cnw1, cnb1,
      fcW, fcb, (float*)d_out);
}

// Round 2
// 5770.324 us; speedup vs baseline: 1.5616x; 1.5616x over previous
//
#include <hip/hip_runtime.h>

// ---------------------------------------------------------------------------
// MultiLayerNormGRU on MI355X (gfx950) — round 2: layer-split + x-precompute +
// fully weight-resident recurrent kernels.
//
// A: P0 = bf16( x @ Wx0^T )          (K=64,  all CUs, chunked over T)
// B: layer-0 recurrence, h-part weights resident (gates: 128 VGPR/wave,
//    cand: 128 KB LDS). Reads P0, writes h0 sequence. 32 blocks.
// C: P1 = bf16( h0 @ Wx1^T )         (K=256, all CUs)
// D: layer-1 recurrence (same shapes) + final FC head kernel.
// P layout transposed to [..][col][16 rows] so per-step per-lane precomp
// fetches are 6x ushort4 coalesced loads issued before the gates MFMA.
// ---------------------------------------------------------------------------

#define B_   512
#define T_   512
#define DIN  64
#define H_   256
#define OUT_ 64
#define EPS_ 1e-5f

typedef __attribute__((ext_vector_type(8))) short bf16x8;
typedef __attribute__((ext_vector_type(4))) float f32x4;

__device__ __forceinline__ unsigned short f2bf(float f) {
  unsigned int u = __float_as_uint(f);
  u += 0x7fffu + ((u >> 16) & 1u);          // RNE f32 -> bf16
  return (unsigned short)(u >> 16);
}
__device__ __forceinline__ float bfh(unsigned short u) {
  return __uint_as_float(((unsigned int)u) << 16);
}
__device__ __forceinline__ float sigm(float xv) { return 1.f / (1.f + __expf(-xv)); }
__device__ __forceinline__ float tanh_fast(float xv) {
  xv = fminf(fmaxf(xv, -15.f), 15.f);
  float e = __expf(-2.f * xv);
  return (1.f - e) / (1.f + e);
}

struct CellParams {
  float bg_r0, bg_r1, bg_z0, bg_z1;
  float gw_r0, gw_r1, gw_z0, gw_z1;
  float gb_r0, gb_r1, gb_z0, gb_z1;
  float bc_0, bc_1, cw_0, cw_1, cb_0, cb_1;
};

// ------------------------- prep: weight fragments ---------------------------
// h-part weights -> MFMA B-fragments (KC=8, K=256), frag-linear:
// dst[((nt*8 + kc)*64 + lane)*8 + e], lane=(n&15)+16*((k>>3)&3), e=k&7.
__global__ void prep_frag(const float* __restrict__ w, unsigned short* __restrict__ dst,
                          int N, int Ksrc, int koff) {
  int gid = blockIdx.x * 256 + threadIdx.x;
  if (gid >= N * 256) return;
  int n = gid >> 8, k = gid & 255;
  int idx = (((n >> 4) * 8 + (k >> 5)) * 64 + ((n & 15) + 16 * ((k >> 3) & 3))) * 8 + (k & 7);
  dst[idx] = f2bf(w[(size_t)n * Ksrc + koff + k]);
}

// x-part weights -> row-major [768][KX]: rows 0..511 = Wg[:, :KX], 512..767 = Wc[:, :KX]
__global__ void prep_wx(const float* __restrict__ wg, const float* __restrict__ wc,
                        unsigned short* __restrict__ dst, int KX, int Kg, int Kc) {
  int gid = blockIdx.x * 256 + threadIdx.x;
  if (gid >= 768 * KX) return;
  int n = gid / KX, k = gid - n * KX;
  float v = (n < 512) ? wg[(size_t)n * Kg + k] : wc[(size_t)(n - 512) * Kc + k];
  dst[gid] = f2bf(v);
}

// ------------------------- precomp GEMM (phases A, C) -----------------------
// M-chunk = 512*TC rows ordered m=(bt*TC+tt)*16+r ; N=768 ; K=KX.
// BM=128, BN=128, BK=64, 4 waves (2x2), each 64x64. Output in transposed
// P layout: Pc[((bt*TC+tt)*768 + n)*16 + r] bf16.
template<int KX, bool AFP32>
__launch_bounds__(256)
__global__ void precomp(const void* __restrict__ Asrc,
                        const unsigned short* __restrict__ wx,
                        unsigned short* __restrict__ Pc,
                        int TC, int t0)
{
  __shared__ __align__(16) unsigned short A_s[8 * 2 * 64 * 8];
  __shared__ __align__(16) unsigned short B_s[8 * 2 * 64 * 8];

  const int tid = threadIdx.x, lane = tid & 63, wv = tid >> 6;
  const int m0 = blockIdx.x * 128, nb = blockIdx.y * 128;
  const int bt = m0 / (TC * 16);
  const int tt0 = (m0 - bt * TC * 16) >> 4;
  const int mq = wv >> 1, nq = wv & 1;
  const int crow0 = (lane >> 4) * 4;

  f32x4 acc[4][4];
#pragma unroll
  for (int i = 0; i < 4; ++i)
#pragma unroll
    for (int j = 0; j < 4; ++j) acc[i][j] = (f32x4){0, 0, 0, 0};

  for (int kb = 0; kb < KX / 64; ++kb) {
    __syncthreads();
#pragma unroll
    for (int it = 0; it < 4; ++it) {
      int s = tid + it * 256;
      int rg = s >> 3, k8 = s & 7;
      int mt = rg >> 4, r15 = rg & 15;
      int dl = r15 + 16 * (k8 & 3), kc = k8 >> 2;
      if (AFP32) {
        const float* xp = (const float*)Asrc +
            (((size_t)(bt * 16 + r15)) * T_ + (t0 + tt0 + mt)) * DIN + kb * 64 + k8 * 8;
        float4 u0 = *(const float4*)xp, u1 = *(const float4*)(xp + 4);
        unsigned short tmp[8];
        tmp[0] = f2bf(u0.x); tmp[1] = f2bf(u0.y); tmp[2] = f2bf(u0.z); tmp[3] = f2bf(u0.w);
        tmp[4] = f2bf(u1.x); tmp[5] = f2bf(u1.y); tmp[6] = f2bf(u1.z); tmp[7] = f2bf(u1.w);
        *reinterpret_cast<bf16x8*>(&A_s[((mt * 2 + kc) * 64 + dl) * 8]) =
            *reinterpret_cast<bf16x8*>(tmp);
      } else {
        const unsigned short* ap = (const unsigned short*)Asrc +
            ((size_t)(m0 + rg)) * KX + kb * 64 + k8 * 8;
        *reinterpret_cast<bf16x8*>(&A_s[((mt * 2 + kc) * 64 + dl) * 8]) =
            *reinterpret_cast<const bf16x8*>(ap);
      }
      const unsigned short* bp = wx + ((size_t)(nb + rg)) * KX + kb * 64 + k8 * 8;
      *reinterpret_cast<bf16x8*>(&B_s[((mt * 2 + kc) * 64 + dl) * 8]) =
          *reinterpret_cast<const bf16x8*>(bp);
    }
    __syncthreads();
#pragma unroll
    for (int kc = 0; kc < 2; ++kc) {
      bf16x8 av[4], bv[4];
#pragma unroll
      for (int i = 0; i < 4; ++i) {
        av[i] = *reinterpret_cast<const bf16x8*>(&A_s[(((mq * 4 + i) * 2 + kc) * 64 + lane) * 8]);
        bv[i] = *reinterpret_cast<const bf16x8*>(&B_s[(((nq * 4 + i) * 2 + kc) * 64 + lane) * 8]);
      }
#pragma unroll
      for (int i = 0; i < 4; ++i)
#pragma unroll
        for (int j = 0; j < 4; ++j)
          acc[i][j] = __builtin_amdgcn_mfma_f32_16x16x32_bf16(av[i], bv[j], acc[i][j], 0, 0, 0);
    }
  }
#pragma unroll
  for (int i = 0; i < 4; ++i) {
    int tt = tt0 + mq * 4 + i;
#pragma unroll
    for (int j = 0; j < 4; ++j) {
      int n = nb + nq * 64 + j * 16 + (lane & 15);
      ushort4 o;
      o.x = f2bf(acc[i][j][0]); o.y = f2bf(acc[i][j][1]);
      o.z = f2bf(acc[i][j][2]); o.w = f2bf(acc[i][j][3]);
      *reinterpret_cast<ushort4*>(&Pc[((size_t)(bt * TC + tt) * 768 + n) * 16 + crow0]) = o;
    }
  }
}

// ------------------------- recurrent kernel (phases B, D) -------------------
template<bool FIRST, bool L0>
__launch_bounds__(512)
__global__ void gru_layer(
    const unsigned short* __restrict__ gfrag,   // [32nt][8kc][64][8] gates h-part
    const unsigned short* __restrict__ cfrag,   // [16nt][8kc][64][8] cand h-part
    const unsigned short* __restrict__ Pc,      // transposed precomp chunk
    const float* __restrict__ bg, const float* __restrict__ gnw, const float* __restrict__ gnb,
    const float* __restrict__ bc, const float* __restrict__ cnw, const float* __restrict__ cnb,
    float* __restrict__ hstate,                 // [512][256] fp32 carry
    unsigned short* __restrict__ h0out,         // L0: h0 chunk [(bt*TC+tt)*16+r][256]
    int TC)
{
  __shared__ __align__(16) unsigned short wc_s[16 * 8 * 64 * 8];  // 128 KB cand weights
  __shared__ __align__(16) unsigned short h_s[16][264];
  __shared__ __align__(16) unsigned short rh_s[16][264];
  __shared__ float sumP[8][16];
  __shared__ float sqP[8][16];

  const int tid = threadIdx.x, lane = tid & 63, wv = tid >> 6;
  const int bt = blockIdx.x, b0 = bt * 16;
  const int arow = lane & 15, koff = (lane >> 4) * 8, crow0 = (lane >> 4) * 4;
  const int colr0 = 32 * wv + (lane & 15), colr1 = colr0 + 16;
  const int nt0 = 2 * wv, nt1 = 2 * wv + 1, nt2 = 16 + 2 * wv, nt3 = 17 + 2 * wv;

  // cand weights -> LDS (one-time)
  for (int i = tid; i < 8192; i += 512)
    *reinterpret_cast<bf16x8*>(&wc_s[i * 8]) = *reinterpret_cast<const bf16x8*>(&cfrag[i * 8]);

  // gate weights -> registers (4 ntiles x 8 kc = 128 VGPRs)
  bf16x8 wgr0[8], wgr1[8], wgr2[8], wgr3[8];
#pragma unroll
  for (int kc = 0; kc < 8; ++kc) {
    wgr0[kc] = *reinterpret_cast<const bf16x8*>(&gfrag[((nt0 * 8 + kc) * 64 + lane) * 8]);
    wgr1[kc] = *reinterpret_cast<const bf16x8*>(&gfrag[((nt1 * 8 + kc) * 64 + lane) * 8]);
    wgr2[kc] = *reinterpret_cast<const bf16x8*>(&gfrag[((nt2 * 8 + kc) * 64 + lane) * 8]);
    wgr3[kc] = *reinterpret_cast<const bf16x8*>(&gfrag[((nt3 * 8 + kc) * 64 + lane) * 8]);
  }

  CellParams p;
  p.bg_r0 = bg[colr0];      p.bg_r1 = bg[colr1];
  p.bg_z0 = bg[256 + colr0]; p.bg_z1 = bg[256 + colr1];
  p.gw_r0 = gnw[colr0];     p.gw_r1 = gnw[colr1];
  p.gw_z0 = gnw[256 + colr0]; p.gw_z1 = gnw[256 + colr1];
  p.gb_r0 = gnb[colr0];     p.gb_r1 = gnb[colr1];
  p.gb_z0 = gnb[256 + colr0]; p.gb_z1 = gnb[256 + colr1];
  p.bc_0 = bc[colr0];  p.bc_1 = bc[colr1];
  p.cw_0 = cnw[colr0]; p.cw_1 = cnw[colr1];
  p.cb_0 = cnb[colr0]; p.cb_1 = cnb[colr1];

  float hm[2][4];
  if (FIRST) {
#pragma unroll
    for (int g = 0; g < 4; ++g) { hm[0][g] = 0.f; hm[1][g] = 0.f; }
    for (int i = tid; i < 16 * 264; i += 512) (&h_s[0][0])[i] = 0;
  } else {
#pragma unroll
    for (int g = 0; g < 4; ++g) {
      hm[0][g] = hstate[(size_t)(b0 + crow0 + g) * 256 + colr0];
      hm[1][g] = hstate[(size_t)(b0 + crow0 + g) * 256 + colr1];
    }
    { // h_s from fp32 state (512 threads x 8 values)
      int r = tid >> 5, c8 = (tid & 31) * 8;
      float4 v0 = *reinterpret_cast<const float4*>(&hstate[(size_t)(b0 + r) * 256 + c8]);
      float4 v1 = *reinterpret_cast<const float4*>(&hstate[(size_t)(b0 + r) * 256 + c8 + 4]);
      ushort4 o0, o1;
      o0.x = f2bf(v0.x); o0.y = f2bf(v0.y); o0.z = f2bf(v0.z); o0.w = f2bf(v0.w);
      o1.x = f2bf(v1.x); o1.y = f2bf(v1.y); o1.z = f2bf(v1.z); o1.w = f2bf(v1.w);
      *reinterpret_cast<ushort4*>(&h_s[r][c8]) = o0;
      *reinterpret_cast<ushort4*>(&h_s[r][c8 + 4]) = o1;
    }
  }
  __syncthreads();

  for (int tt = 0; tt < TC; ++tt) {
    // prefetch per-lane precomp values (independent of MFMA -> latency hidden)
    const unsigned short* Pb = Pc + ((size_t)(bt * TC + tt) * 768) * 16;
    ushort4 pv0 = *reinterpret_cast<const ushort4*>(Pb + (size_t)colr0 * 16 + crow0);
    ushort4 pv1 = *reinterpret_cast<const ushort4*>(Pb + (size_t)colr1 * 16 + crow0);
    ushort4 pv2 = *reinterpret_cast<const ushort4*>(Pb + (size_t)(256 + colr0) * 16 + crow0);
    ushort4 pv3 = *reinterpret_cast<const ushort4*>(Pb + (size_t)(256 + colr1) * 16 + crow0);
    ushort4 pv4 = *reinterpret_cast<const ushort4*>(Pb + (size_t)(512 + colr0) * 16 + crow0);
    ushort4 pv5 = *reinterpret_cast<const ushort4*>(Pb + (size_t)(512 + colr1) * 16 + crow0);

    // ---- gates MFMA (weights in registers) ----
    f32x4 a0 = {0, 0, 0, 0}, a1 = {0, 0, 0, 0}, a2 = {0, 0, 0, 0}, a3 = {0, 0, 0, 0};
#pragma unroll
    for (int kc = 0; kc < 8; ++kc) {
      bf16x8 av = *reinterpret_cast<const bf16x8*>(&h_s[arow][kc * 32 + koff]);
      a0 = __builtin_amdgcn_mfma_f32_16x16x32_bf16(av, wgr0[kc], a0, 0, 0, 0);
      a1 = __builtin_amdgcn_mfma_f32_16x16x32_bf16(av, wgr1[kc], a1, 0, 0, 0);
      a2 = __builtin_amdgcn_mfma_f32_16x16x32_bf16(av, wgr2[kc], a2, 0, 0, 0);
      a3 = __builtin_amdgcn_mfma_f32_16x16x32_bf16(av, wgr3[kc], a3, 0, 0, 0);
    }
    {
      float s[4], q[4];
#pragma unroll
      for (int g = 0; g < 4; ++g) {
        a0[g] += p.bg_r0 + bfh(((const unsigned short*)&pv0)[g]);
        a1[g] += p.bg_r1 + bfh(((const unsigned short*)&pv1)[g]);
        a2[g] += p.bg_z0 + bfh(((const unsigned short*)&pv2)[g]);
        a3[g] += p.bg_z1 + bfh(((const unsigned short*)&pv3)[g]);
        s[g] = a0[g] + a1[g] + a2[g] + a3[g];
        q[g] = a0[g] * a0[g] + a1[g] * a1[g] + a2[g] * a2[g] + a3[g] * a3[g];
      }
#pragma unroll
      for (int m = 1; m < 16; m <<= 1) {
#pragma unroll
        for (int g = 0; g < 4; ++g) { s[g] += __shfl_xor(s[g], m, 64); q[g] += __shfl_xor(q[g], m, 64); }
      }
      if ((lane & 15) == 0) {
#pragma unroll
        for (int g = 0; g < 4; ++g) { sumP[wv][crow0 + g] = s[g]; sqP[wv][crow0 + g] = q[g]; }
      }
    }
    __syncthreads();

    // ---- gate LN, r,z; write r*h ----
    float zf[2][4];
    {
      const int rr = lane & 15;
      float S = 0.f, Q = 0.f;
#pragma unroll
      for (int w = 0; w < 8; ++w) { S += sumP[w][rr]; Q += sqP[w][rr]; }
      float mn = S * (1.f / 512.f);
      float rs = rsqrtf(Q * (1.f / 512.f) - mn * mn + EPS_);
#pragma unroll
      for (int g = 0; g < 4; ++g) {
        float m_ = __shfl(mn, crow0 + g, 64);
        float r_ = __shfl(rs, crow0 + g, 64);
        float r0 = sigm((a0[g] - m_) * r_ * p.gw_r0 + p.gb_r0);
        float r1 = sigm((a1[g] - m_) * r_ * p.gw_r1 + p.gb_r1);
        rh_s[crow0 + g][colr0] = f2bf(r0 * hm[0][g]);
        rh_s[crow0 + g][colr1] = f2bf(r1 * hm[1][g]);
        zf[0][g] = sigm((a2[g] - m_) * r_ * p.gw_z0 + p.gb_z0);
        zf[1][g] = sigm((a3[g] - m_) * r_ * p.gw_z1 + p.gb_z1);
      }
    }
    __syncthreads();

    // ---- cand MFMA (weights in LDS) ----
    f32x4 c0 = {0, 0, 0, 0}, c1 = {0, 0, 0, 0};
#pragma unroll
    for (int kc = 0; kc < 8; ++kc) {
      bf16x8 av = *reinterpret_cast<const bf16x8*>(&rh_s[arow][kc * 32 + koff]);
      bf16x8 b0v = *reinterpret_cast<const bf16x8*>(&wc_s[((nt0 * 8 + kc) * 64 + lane) * 8]);
      bf16x8 b1v = *reinterpret_cast<const bf16x8*>(&wc_s[((nt1 * 8 + kc) * 64 + lane) * 8]);
      c0 = __builtin_amdgcn_mfma_f32_16x16x32_bf16(av, b0v, c0, 0, 0, 0);
      c1 = __builtin_amdgcn_mfma_f32_16x16x32_bf16(av, b1v, c1, 0, 0, 0);
    }
    {
      float s[4], q[4];
#pragma unroll
      for (int g = 0; g < 4; ++g) {
        c0[g] += p.bc_0 + bfh(((const unsigned short*)&pv4)[g]);
        c1[g] += p.bc_1 + bfh(((const unsigned short*)&pv5)[g]);
        s[g] = c0[g] + c1[g];
        q[g] = c0[g] * c0[g] + c1[g] * c1[g];
      }
#pragma unroll
      for (int m = 1; m < 16; m <<= 1) {
#pragma unroll
        for (int g = 0; g < 4; ++g) { s[g] += __shfl_xor(s[g], m, 64); q[g] += __shfl_xor(q[g], m, 64); }
      }
      if ((lane & 15) == 0) {
#pragma unroll
        for (int g = 0; g < 4; ++g) { sumP[wv][crow0 + g] = s[g]; sqP[wv][crow0 + g] = q[g]; }
      }
    }
    __syncthreads();

    // ---- cand LN, tanh, h update ----
    {
      const int rr = lane & 15;
      float S = 0.f, Q = 0.f;
#pragma unroll
      for (int w = 0; w < 8; ++w) { S += sumP[w][rr]; Q += sqP[w][rr]; }
      float mn = S * (1.f / 256.f);
      float rs = rsqrtf(Q * (1.f / 256.f) - mn * mn + EPS_);
      unsigned short* hrow = L0 ? (h0out + (size_t)(bt * TC + tt) * 16 * 256) : (unsigned short*)nullptr;
#pragma unroll
      for (int g = 0; g < 4; ++g) {
        float m_ = __shfl(mn, crow0 + g, 64);
        float r_ = __shfl(rs, crow0 + g, 64);
        float n0 = tanh_fast((c0[g] - m_) * r_ * p.cw_0 + p.cb_0);
        float n1 = tanh_fast((c1[g] - m_) * r_ * p.cw_1 + p.cb_1);
        float h0n = (1.f - zf[0][g]) * hm[0][g] + zf[0][g] * n0;
        float h1n = (1.f - zf[1][g]) * hm[1][g] + zf[1][g] * n1;
        hm[0][g] = h0n; hm[1][g] = h1n;
        unsigned short hb0 = f2bf(h0n), hb1 = f2bf(h1n);
        h_s[crow0 + g][colr0] = hb0;
        h_s[crow0 + g][colr1] = hb1;
        if (L0) {
          hrow[(size_t)(crow0 + g) * 256 + colr0] = hb0;
          hrow[(size_t)(crow0 + g) * 256 + colr1] = hb1;
        }
      }
    }
    __syncthreads();
  }

  // carry state (fp32)
#pragma unroll
  for (int g = 0; g < 4; ++g) {
    hstate[(size_t)(b0 + crow0 + g) * 256 + colr0] = hm[0][g];
    hstate[(size_t)(b0 + crow0 + g) * 256 + colr1] = hm[1][g];
  }
}

// ------------------------------- FC head ------------------------------------
__launch_bounds__(256)
__global__ void head_k(const float* __restrict__ h1, const float* __restrict__ fcW,
                       const float* __restrict__ fcb, float* __restrict__ out) {
  __shared__ float hs[16][256];
  const int tid = threadIdx.x, b0 = blockIdx.x * 16;
  for (int i = tid; i < 16 * 64; i += 256) {
    int r = i >> 6, c4 = (i & 63) * 4;
    *reinterpret_cast<float4*>(&hs[r][c4]) =
        *reinterpret_cast<const float4*>(&h1[(size_t)(b0 + r) * 256 + c4]);
  }
  __syncthreads();
  int r = tid >> 4, o = (tid & 15) * 4;
  float a0 = fcb[o], a1 = fcb[o + 1], a2 = fcb[o + 2], a3 = fcb[o + 3];
  for (int k = 0; k < 256; ++k) {
    float h = hs[r][k];
    a0 = fmaf(h, fcW[(size_t)(o + 0) * 256 + k], a0);
    a1 = fmaf(h, fcW[(size_t)(o + 1) * 256 + k], a1);
    a2 = fmaf(h, fcW[(size_t)(o + 2) * 256 + k], a2);
    a3 = fmaf(h, fcW[(size_t)(o + 3) * 256 + k], a3);
  }
  float4 ov = {a0, a1, a2, a3};
  *reinterpret_cast<float4*>(&out[(size_t)(b0 + r) * 64 + o]) = ov;
}

// --------------------------------- host -------------------------------------
extern "C" void kernel_launch(void* const* d_in, const int* in_sizes, int n_in,
                              void* d_out, int out_size, void* d_ws, size_t ws_size,
                              hipStream_t stream) {
  (void)in_sizes; (void)n_in; (void)out_size;
  const float* x    = (const float*)d_in[0];
  const float* Wg0  = (const float*)d_in[1];
  const float* bg0  = (const float*)d_in[2];
  const float* gnw0 = (const float*)d_in[3];
  const float* gnb0 = (const float*)d_in[4];
  const float* Wc0  = (const float*)d_in[5];
  const float* bc0  = (const float*)d_in[6];
  const float* cnw0 = (const float*)d_in[7];
  const float* cnb0 = (const float*)d_in[8];
  const float* Wg1  = (const float*)d_in[9];
  const float* bg1  = (const float*)d_in[10];
  const float* gnw1 = (const float*)d_in[11];
  const float* gnb1 = (const float*)d_in[12];
  const float* Wc1  = (const float*)d_in[13];
  const float* bc1  = (const float*)d_in[14];
  const float* cnw1 = (const float*)d_in[15];
  const float* cnb1 = (const float*)d_in[16];
  const float* fcW  = (const float*)d_in[17];
  const float* fcb  = (const float*)d_in[18];

  // choose T-chunk so workspace fits: need = frags + states + TC*(h0 + 2*P)
  const size_t frag_bytes = (size_t)(131072 + 65536 + 131072 + 65536 + 49152 + 196608) * 2;
  int TC = 128;
  while (TC > 8) {
    size_t need = frag_bytes + 2 * 131072 * 4 + (size_t)TC * (262144 + 2 * 786432);
    if (need <= ws_size) break;
    TC >>= 1;
  }
  const int NC = T_ / TC;

  unsigned short* g0h = (unsigned short*)d_ws;
  unsigned short* c0h = g0h + 131072;
  unsigned short* g1h = c0h + 65536;
  unsigned short* c1h = g1h + 131072;
  unsigned short* wx0 = c1h + 65536;
  unsigned short* wx1 = wx0 + 49152;
  unsigned short* P0c = wx1 + 196608;
  unsigned short* P1c = P0c + (size_t)TC * 393216;
  unsigned short* h0c = P1c + (size_t)TC * 393216;
  float* hst0 = (float*)(h0c + (size_t)TC * 131072);
  float* hst1 = hst0 + 131072;

  prep_frag<<<512, 256, 0, stream>>>(Wg0, g0h, 512, 320, 64);
  prep_frag<<<256, 256, 0, stream>>>(Wc0, c0h, 256, 320, 64);
  prep_frag<<<512, 256, 0, stream>>>(Wg1, g1h, 512, 512, 256);
  prep_frag<<<256, 256, 0, stream>>>(Wc1, c1h, 256, 512, 256);
  prep_wx<<<192, 256, 0, stream>>>(Wg0, Wc0, wx0, 64, 320, 320);
  prep_wx<<<768, 256, 0, stream>>>(Wg1, Wc1, wx1, 256, 512, 512);

  dim3 pgrid(4 * TC, 6);
  for (int c = 0; c < NC; ++c) {
    precomp<64, true><<<pgrid, 256, 0, stream>>>(x, wx0, P0c, TC, c * TC);
    if (c == 0)
      gru_layer<true, true><<<32, 512, 0, stream>>>(g0h, c0h, P0c,
          bg0, gnw0, gnb0, bc0, cnw0, cnb0, hst0, h0c, TC);
    else
      gru_layer<false, true><<<32, 512, 0, stream>>>(g0h, c0h, P0c,
          bg0, gnw0, gnb0, bc0, cnw0, cnb0, hst0, h0c, TC);
    precomp<256, false><<<pgrid, 256, 0, stream>>>(h0c, wx1, P1c, TC, 0);
    if (c == 0)
      gru_layer<true, false><<<32, 512, 0, stream>>>(g1h, c1h, P1c,
          bg1, gnw1, gnb1, bc1, cnw1, cnb1, hst1, (unsigned short*)nullptr, TC);
    else
      gru_layer<false, false><<<32, 512, 0, stream>>>(g1h, c1h, P1c,
          bg1, gnw1, gnb1, bc1, cnw1, cnb1, hst1, (unsigned short*)nullptr, TC);
  }
  head_k<<<32, 256, 0, stream>>>(hst1, fcW, fcb, (float*)d_out);
}